// Round 1
// baseline (293.769 us; speedup 1.0000x reference)
//
#include <hip/hip_runtime.h>
#include <hip/hip_bf16.h>

#define S_LEN 2048
#define DH 64
#define QBLK 128
#define KVBLK 64
#define LDP 72   // padded row length (bf16 elems): 144B rows, bank stride 36%32=4

typedef __attribute__((ext_vector_type(4))) float f32x4;
typedef __attribute__((ext_vector_type(8))) short short8v;
typedef __attribute__((ext_vector_type(4))) short short4v;

__device__ __forceinline__ short f2bf(float f) {
    unsigned u = __builtin_bit_cast(unsigned, f);
    u = (u + 0x7fffu + ((u >> 16) & 1u)) >> 16;
    return (short)u;
}

__global__ __launch_bounds__(256) void fa_fwd_kernel(
    const float* __restrict__ Q, const float* __restrict__ K,
    const float* __restrict__ V, float* __restrict__ O)
{
    const int tid  = threadIdx.x;
    const int lane = tid & 63;
    const int w    = tid >> 6;
    const int qb   = blockIdx.x & 15;   // q-block within head (16 of them)
    const int bh   = blockIdx.x >> 4;   // which (b,h)

    const size_t base = (size_t)bh * S_LEN * DH;
    const float* Qg = Q + base;
    const float* Kg = K + base;
    const float* Vg = V + base;
    float*       Og = O + base;

    __shared__ short K_lds[KVBLK][LDP];     // [kv][d]
    __shared__ short V_lds[DH][LDP];        // transposed: [d][kv]
    __shared__ short P_lds[4][32][LDP];     // per-wave [rt*16+row][kv]

    const int lr = lane & 15;   // 0..15
    const int lg = lane >> 4;   // 0..3

    // ---- hoist Q fragments (scale folded in; exact pow2) ----
    const int q0 = qb * QBLK + w * 32;
    short8v qfrag[2][2];
    #pragma unroll
    for (int rt = 0; rt < 2; ++rt) {
        #pragma unroll
        for (int kf = 0; kf < 2; ++kf) {
            const float* qp = Qg + (size_t)(q0 + rt * 16 + lr) * DH + kf * 32 + lg * 8;
            f32x4 a = *(const f32x4*)qp;
            f32x4 b = *(const f32x4*)(qp + 4);
            short8v f;
            f[0] = f2bf(a[0] * 0.125f); f[1] = f2bf(a[1] * 0.125f);
            f[2] = f2bf(a[2] * 0.125f); f[3] = f2bf(a[3] * 0.125f);
            f[4] = f2bf(b[0] * 0.125f); f[5] = f2bf(b[1] * 0.125f);
            f[6] = f2bf(b[2] * 0.125f); f[7] = f2bf(b[3] * 0.125f);
            qfrag[rt][kf] = f;
        }
    }

    f32x4 o_acc[2][4];
    float m_run[2][4], l_run[2][4];
    #pragma unroll
    for (int rt = 0; rt < 2; ++rt)
        #pragma unroll
        for (int i = 0; i < 4; ++i) {
            o_acc[rt][i] = (f32x4){0.f, 0.f, 0.f, 0.f};
            m_run[rt][i] = -1e30f;
            l_run[rt][i] = 0.f;
        }

    const int kv_end = (qb + 1) * QBLK;   // causal extent for this q-block

    for (int kvb = 0; kvb < kv_end; kvb += KVBLK) {
        __syncthreads();   // protect K_lds/V_lds from previous iteration's readers

        // ---- stage K tile: 64x64 fp32 -> bf16, float4 reads, b64 LDS writes ----
        #pragma unroll
        for (int i = 0; i < 4; ++i) {
            int id = i * 256 + tid;          // 0..1023 float4s
            int kr = id >> 4;                // row 0..63
            int dc = (id & 15) * 4;          // col 0,4,...,60
            f32x4 vv = *(const f32x4*)(Kg + (size_t)(kvb + kr) * DH + dc);
            short4v s4;
            s4[0] = f2bf(vv[0]); s4[1] = f2bf(vv[1]);
            s4[2] = f2bf(vv[2]); s4[3] = f2bf(vv[3]);
            *(short4v*)&K_lds[kr][dc] = s4;
        }

        // ---- stage V transposed: coalesced row reads, packed b32 transposed writes ----
        {
            int d  = tid & 63;
            int g4 = tid >> 6;
            #pragma unroll
            for (int i = 0; i < 16; i += 2) {
                int kv = g4 * 16 + i;
                float a = Vg[(size_t)(kvb + kv) * DH + d];
                float b = Vg[(size_t)(kvb + kv + 1) * DH + d];
                unsigned pk = (unsigned)(unsigned short)f2bf(a) |
                              ((unsigned)(unsigned short)f2bf(b) << 16);
                *(unsigned*)((char*)&V_lds[0][0] + d * (LDP * 2) + kv * 2) = pk;
            }
        }
        __syncthreads();

        // ---- QK^T: S[rt][kt] = Q * K^T ----
        short8v kfrag[4][2];
        #pragma unroll
        for (int kt = 0; kt < 4; ++kt)
            #pragma unroll
            for (int kf = 0; kf < 2; ++kf)
                kfrag[kt][kf] = *(const short8v*)&K_lds[kt * 16 + lr][kf * 32 + lg * 8];

        f32x4 s_acc[2][4];
        #pragma unroll
        for (int rt = 0; rt < 2; ++rt)
            #pragma unroll
            for (int kt = 0; kt < 4; ++kt)
                s_acc[rt][kt] = (f32x4){0.f, 0.f, 0.f, 0.f};

        #pragma unroll
        for (int kt = 0; kt < 4; ++kt)
            #pragma unroll
            for (int kf = 0; kf < 2; ++kf)
                #pragma unroll
                for (int rt = 0; rt < 2; ++rt)
                    s_acc[rt][kt] = __builtin_amdgcn_mfma_f32_16x16x32_bf16(
                        qfrag[rt][kf], kfrag[kt][kf], s_acc[rt][kt], 0, 0, 0);

        // ---- mask (diagonal blocks only) + online softmax, fully wave-parallel ----
        const bool needmask = (kvb + KVBLK - 1) > q0;
        #pragma unroll
        for (int rt = 0; rt < 2; ++rt) {
            #pragma unroll
            for (int r = 0; r < 4; ++r) {
                const int qrow = q0 + rt * 16 + lg * 4 + r;
                if (needmask) {
                    #pragma unroll
                    for (int kt = 0; kt < 4; ++kt) {
                        int kvv = kvb + kt * 16 + lr;
                        if (kvv > qrow) s_acc[rt][kt][r] = -1e30f;
                    }
                }
                float tmax = fmaxf(fmaxf(s_acc[rt][0][r], s_acc[rt][1][r]),
                                   fmaxf(s_acc[rt][2][r], s_acc[rt][3][r]));
                tmax = fmaxf(tmax, __shfl_xor(tmax, 1));
                tmax = fmaxf(tmax, __shfl_xor(tmax, 2));
                tmax = fmaxf(tmax, __shfl_xor(tmax, 4));
                tmax = fmaxf(tmax, __shfl_xor(tmax, 8));
                float mnew = fmaxf(m_run[rt][r], tmax);
                float corr = __expf(m_run[rt][r] - mnew);
                m_run[rt][r] = mnew;
                float rsum = 0.f;
                #pragma unroll
                for (int kt = 0; kt < 4; ++kt) {
                    float p = __expf(s_acc[rt][kt][r] - mnew);
                    s_acc[rt][kt][r] = p;
                    rsum += p;
                }
                rsum += __shfl_xor(rsum, 1);
                rsum += __shfl_xor(rsum, 2);
                rsum += __shfl_xor(rsum, 4);
                rsum += __shfl_xor(rsum, 8);
                l_run[rt][r] = l_run[rt][r] * corr + rsum;
                #pragma unroll
                for (int dt = 0; dt < 4; ++dt)
                    o_acc[rt][dt][r] *= corr;
            }
        }

        // ---- P -> LDS (wave-private), then PV MFMAs ----
        #pragma unroll
        for (int rt = 0; rt < 2; ++rt)
            #pragma unroll
            for (int kt = 0; kt < 4; ++kt)
                #pragma unroll
                for (int r = 0; r < 4; ++r)
                    P_lds[w][rt * 16 + lg * 4 + r][kt * 16 + lr] = f2bf(s_acc[rt][kt][r]);

        short8v pfrag[2][2];
        #pragma unroll
        for (int rt = 0; rt < 2; ++rt)
            #pragma unroll
            for (int kf = 0; kf < 2; ++kf)
                pfrag[rt][kf] = *(const short8v*)&P_lds[w][rt * 16 + lr][kf * 32 + lg * 8];

        #pragma unroll
        for (int dt = 0; dt < 4; ++dt) {
            const char* vb = (const char*)&V_lds[0][0] + (dt * 16 + lr) * (LDP * 2);
            short8v v0 = *(const short8v*)(vb + (lg * 8) * 2);
            short8v v1 = *(const short8v*)(vb + (32 + lg * 8) * 2);
            #pragma unroll
            for (int rt = 0; rt < 2; ++rt) {
                o_acc[rt][dt] = __builtin_amdgcn_mfma_f32_16x16x32_bf16(
                    pfrag[rt][0], v0, o_acc[rt][dt], 0, 0, 0);
                o_acc[rt][dt] = __builtin_amdgcn_mfma_f32_16x16x32_bf16(
                    pfrag[rt][1], v1, o_acc[rt][dt], 0, 0, 0);
            }
        }
    }

    // ---- epilogue: divide by l, write fp32 ----
    #pragma unroll
    for (int rt = 0; rt < 2; ++rt) {
        #pragma unroll
        for (int r = 0; r < 4; ++r) {
            float inv = 1.0f / l_run[rt][r];
            int qrow = q0 + rt * 16 + lg * 4 + r;
            float* op = Og + (size_t)qrow * DH + lr;
            #pragma unroll
            for (int dt = 0; dt < 4; ++dt)
                op[dt * 16] = o_acc[rt][dt][r] * inv;
        }
    }
}

extern "C" void kernel_launch(void* const* d_in, const int* in_sizes, int n_in,
                              void* d_out, int out_size, void* d_ws, size_t ws_size,
                              hipStream_t stream) {
    const float* q = (const float*)d_in[0];
    const float* k = (const float*)d_in[1];
    const float* v = (const float*)d_in[2];
    float* out = (float*)d_out;
    // grid: (B*H) * (S/QBLK) = 64 * 16 = 1024 blocks; same-head blocks adjacent for L2 reuse
    fa_fwd_kernel<<<dim3(1024), dim3(256), 0, stream>>>(q, k, v, out);
}